// Round 1
// baseline (527.119 us; speedup 1.0000x reference)
//
#include <hip/hip_runtime.h>
#include <hip/hip_bf16.h>
#include <stdint.h>

// Problem constants (fixed by setup_inputs)
#define T_   24
#define D_   128
#define H_   96
#define W_   128
#define N_   256
#define KP   49      // 7x7 support points
#define KV   2401    // 49*49
#define KVP  2432    // padded to multiple of 64
#define H1   384     // MLP hidden
#define OUTC 256     // MLP out

typedef __attribute__((ext_vector_type(8))) __bf16 bf16x8;
typedef __attribute__((ext_vector_type(4))) float f32x4;

__device__ inline float bf2f(unsigned short u) {
    union { unsigned int i; float f; } v; v.i = ((unsigned int)u) << 16; return v.f;
}
__device__ inline unsigned short f2bf(float f) {
    union { float f; unsigned int i; } v; v.f = f;
    unsigned int i = v.i;
    return (unsigned short)((i + 0x7FFFu + ((i >> 16) & 1u)) >> 16);  // RNE
}

// ---------------- weight transpose/convert (one-time per call) ----------------
__global__ __launch_bounds__(256) void k_w1t(const float* __restrict__ w1,
                                             unsigned short* __restrict__ w1t) {
    int idx = blockIdx.x * 256 + threadIdx.x;           // H1*KVP = 933888
    if (idx >= H1 * KVP) return;
    int n = idx / KVP, k = idx % KVP;
    float v = (k < KV) ? w1[(size_t)k * H1 + n] : 0.f;
    w1t[idx] = f2bf(v);
}
__global__ __launch_bounds__(256) void k_w2t(const float* __restrict__ w2,
                                             unsigned short* __restrict__ w2t) {
    int idx = blockIdx.x * 256 + threadIdx.x;           // OUTC*H1 = 98304
    if (idx >= OUTC * H1) return;
    int j = idx / H1, k = idx % H1;
    w2t[idx] = f2bf(w2[(size_t)k * OUTC + j]);
}

// ---------------- L2 normalize + transpose (T,D,H,W)f32 -> (T,H,W,D)bf16 -----
__global__ __launch_bounds__(256) void k_normalize(const float* __restrict__ fmaps,
                                                   unsigned short* __restrict__ fm0) {
    int bid = blockIdx.x;                 // t*H_ + h
    int t = bid / H_, h = bid % H_;
    int tid = threadIdx.x;
    __shared__ float ssum[256];
    __shared__ float rs[W_];
    __shared__ float tile[64 * 129];
    const float* base = fmaps + (size_t)t * D_ * H_ * W_ + (size_t)h * W_;
    {   // sum of squares per w (reads coalesced in w)
        int w = tid & 127, half = tid >> 7;
        float ss = 0.f;
        for (int d = half * 64; d < half * 64 + 64; ++d) {
            float v = base[(size_t)d * (H_ * W_) + w];
            ss += v * v;
        }
        ssum[tid] = ss;
    }
    __syncthreads();
    if (tid < W_) rs[tid] = rsqrtf(fmaxf(ssum[tid] + ssum[tid + 128], 1e-12f));
    __syncthreads();
    unsigned short* orow = fm0 + (size_t)(t * H_ + h) * (W_ * D_);
    for (int wt = 0; wt < 2; ++wt) {      // transpose 64-w tiles through LDS
        int wl = tid & 63, dg = tid >> 6;
        int w = wt * 64 + wl;
        float r = rs[w];
        for (int d = dg * 32; d < dg * 32 + 32; ++d)
            tile[wl * 129 + d] = base[(size_t)d * (H_ * W_) + w] * r;
        __syncthreads();
        int d2 = tid & 127, wh = tid >> 7;
        for (int i = 0; i < 32; ++i) {
            int wll = wh * 32 + i;
            orow[(size_t)(wt * 64 + wll) * D_ + d2] = f2bf(tile[wll * 129 + d2]);
        }
        __syncthreads();
    }
}

// ---------------- 2x2 avg pool, bf16 in/out, fp32 accum ----------------------
__global__ __launch_bounds__(256) void k_pool(const unsigned short* __restrict__ in,
                                              unsigned short* __restrict__ out,
                                              int Hs, int Ws) {
    int Ho = Hs >> 1, Wo = Ws >> 1;
    size_t total = (size_t)T_ * Ho * Wo * (D_ / 4);
    size_t idx = (size_t)blockIdx.x * 256 + threadIdx.x;
    if (idx >= total) return;
    int d4 = idx & 31;
    size_t p = idx >> 5;
    int x = (int)(p % Wo); p /= Wo;
    int y = (int)(p % Ho); int t = (int)(p / Ho);
    const unsigned short* b0 = in + (((size_t)t * Hs + 2 * y) * Ws + 2 * x) * D_ + d4 * 4;
    const unsigned short* b1r = b0 + (size_t)Ws * D_;
    float acc[4] = {0.f, 0.f, 0.f, 0.f};
#pragma unroll
    for (int j = 0; j < 2; ++j) {
        const unsigned short* bb = j ? b1r : b0;
#pragma unroll
        for (int i = 0; i < 2; ++i) {
            const unsigned short* q = bb + i * D_;
#pragma unroll
            for (int c = 0; c < 4; ++c) acc[c] += bf2f(q[c]);
        }
    }
    unsigned short* o = out + (((size_t)t * Ho + y) * Wo + x) * D_ + d4 * 4;
#pragma unroll
    for (int c = 0; c < 4; ++c) o[c] = f2bf(acc[c] * 0.25f);
}

// ---------------- bilinear sampler: 2 channels per lane ----------------------
__device__ inline float2 bilin2(const unsigned short* __restrict__ fb, int Hs, int Ws,
                                float px, float py, int lane) {
    float x0f = floorf(px), y0f = floorf(py);
    float tx = px - x0f, ty = py - y0f;
    int x0 = (int)x0f, y0 = (int)y0f;
    float acc0 = 0.f, acc1 = 0.f;
#pragma unroll
    for (int dy = 0; dy < 2; ++dy) {
#pragma unroll
        for (int dx = 0; dx < 2; ++dx) {
            int xi = x0 + dx, yi = y0 + dy;
            float w = (dx ? tx : 1.f - tx) * (dy ? ty : 1.f - ty);
            bool valid = (xi >= 0) && (xi < Ws) && (yi >= 0) && (yi < Hs);
            int xc = xi < 0 ? 0 : (xi > Ws - 1 ? Ws - 1 : xi);
            int yc = yi < 0 ? 0 : (yi > Hs - 1 ? Hs - 1 : yi);
            unsigned int pk = *(const unsigned int*)(fb + ((size_t)yc * Ws + xc) * D_ + lane * 2);
            float wv = valid ? w : 0.f;
            acc0 += wv * bf2f((unsigned short)(pk & 0xffffu));
            acc1 += wv * bf2f((unsigned short)(pk >> 16));
        }
    }
    return {acc0, acc1};
}

// ---------------- track-support features: (N,64,128) bf16, rows>=49 zero -----
__global__ __launch_bounds__(256) void k_tf(const unsigned short* __restrict__ fm,
                                            const float* __restrict__ qcoords,
                                            const int* __restrict__ qframes,
                                            unsigned short* __restrict__ tfg,
                                            int Hs, int Ws, float inv) {
    int n = blockIdx.x;
    int wid = threadIdx.x >> 6, lane = threadIdx.x & 63;
    int fidx = qframes[n];
    float qx = qcoords[n * 2 + 0] * inv, qy = qcoords[n * 2 + 1] * inv;
    const unsigned short* fb = fm + (size_t)fidx * Hs * Ws * D_;
    unsigned short* orow = tfg + (size_t)n * 64 * D_;
    for (int k = wid; k < 64; k += 4) {
        float2 v = {0.f, 0.f};
        if (k < KP) {
            float px = qx + (float)(k / 7 - 3);
            float py = qy + (float)(k % 7 - 3);
            v = bilin2(fb, Hs, Ws, px, py, lane);
        }
        unsigned int pk = (unsigned int)f2bf(v.x) | ((unsigned int)f2bf(v.y) << 16);
        *(unsigned int*)(orow + k * D_ + lane * 2) = pk;
    }
}

// ---------------- cf sampling + 49x49 correlation volume via MFMA ------------
// One block per (t,n). LDS tiles 64x128 bf16, XOR-swizzled for conflict-free
// ds_read_b128. vol row-major (6144 x KVP) bf16, pad cols zeroed.
__global__ __launch_bounds__(256) void k_cfvol(const unsigned short* __restrict__ fm,
                                               const float* __restrict__ coords,
                                               const unsigned short* __restrict__ tfg,
                                               unsigned short* __restrict__ vol,
                                               int Hs, int Ws, float inv) {
    __shared__ uint4 tfs4[1024];  // 16KB
    __shared__ uint4 cfs4[1024];  // 16KB
    unsigned char* tfs = (unsigned char*)tfs4;
    unsigned char* cfs = (unsigned char*)cfs4;
    int n = blockIdx.x & (N_ - 1);
    int t = blockIdx.x >> 8;
    int tid = threadIdx.x, wid = tid >> 6, lane = tid & 63;
    // stage tf (copy with swizzle); rows are 256B = 16 units of 16B
#pragma unroll
    for (int it = 0; it < 4; ++it) {
        int e = it * 256 + tid;
        int row = e >> 4, unit = e & 15;
        uint4 v = *(const uint4*)(tfg + (size_t)n * 8192 + row * 128 + unit * 8);
        *(uint4*)(tfs + row * 256 + ((unit * 16) ^ ((row & 7) << 4))) = v;
    }
    // sample cf rows (49 real + 15 zero), each wave owns rows k = wid mod 4
    float cx = coords[((size_t)t * N_ + n) * 2 + 0] * inv;
    float cy = coords[((size_t)t * N_ + n) * 2 + 1] * inv;
    const unsigned short* fb = fm + (size_t)t * Hs * Ws * D_;
    for (int k = wid; k < 64; k += 4) {
        float2 v = {0.f, 0.f};
        if (k < KP) {
            float px = cx + (float)(k / 7 - 3);
            float py = cy + (float)(k % 7 - 3);
            v = bilin2(fb, Hs, Ws, px, py, lane);
        }
        unsigned int pk = (unsigned int)f2bf(v.x) | ((unsigned int)f2bf(v.y) << 16);
        *(unsigned int*)(cfs + k * 256 + ((lane * 4) ^ ((k & 7) << 4))) = pk;
    }
    __syncthreads();
    // MFMA: wave wid computes 16 k-rows x all 64 l-cols
    f32x4 acc[4] = {f32x4{0,0,0,0}, f32x4{0,0,0,0}, f32x4{0,0,0,0}, f32x4{0,0,0,0}};
    int l15 = lane & 15, hi = lane >> 4;
#pragma unroll
    for (int ks = 0; ks < 4; ++ks) {
        int colb = ks * 64 + hi * 16;
        int arow = wid * 16 + l15;
        bf16x8 a = *(const bf16x8*)(cfs + arow * 256 + (colb ^ ((arow & 7) << 4)));
#pragma unroll
        for (int ln = 0; ln < 4; ++ln) {
            int brow = ln * 16 + l15;
            bf16x8 b = *(const bf16x8*)(tfs + brow * 256 + (colb ^ ((brow & 7) << 4)));
            acc[ln] = __builtin_amdgcn_mfma_f32_16x16x32_bf16(a, b, acc[ln], 0, 0, 0);
        }
    }
    size_t rowA = (size_t)t * N_ + n;
    unsigned short* vrow = vol + rowA * KVP;
#pragma unroll
    for (int ln = 0; ln < 4; ++ln) {
#pragma unroll
        for (int r = 0; r < 4; ++r) {
            int kk = wid * 16 + hi * 4 + r;
            int ll = ln * 16 + l15;
            if (kk < KP && ll < KP) vrow[kk * KP + ll] = f2bf(acc[ln][r]);
        }
    }
    if (tid < KVP - KV) vrow[KV + tid] = 0;  // zero pad cols
}

// ---------------- GEMM1: (6144 x KVP) @ w1t^T (384 x KVP) + b1 -> GELU -> bf16
__global__ __launch_bounds__(256) void k_gemm1(const unsigned short* __restrict__ A,
                                               const unsigned short* __restrict__ Bt,
                                               const float* __restrict__ b1,
                                               unsigned short* __restrict__ Hout) {
    __shared__ uint4 As4[1024];  // 128 rows x 128B = 16KB
    __shared__ uint4 Bs4[512];   // 64 rows x 128B = 8KB
    unsigned char* As = (unsigned char*)As4;
    unsigned char* Bs = (unsigned char*)Bs4;
    int bm = blockIdx.x % 48, bn = blockIdx.x / 48;
    int tid = threadIdx.x, lane = tid & 63;
    int wid = tid >> 6, wm = wid & 1, wn = wid >> 1;
    int l15 = lane & 15, hi = lane >> 4;
    f32x4 acc[4][2] = {};
    const int KT = KVP / 64;  // 38
    for (int kt = 0; kt < KT; ++kt) {
#pragma unroll
        for (int it = 0; it < 4; ++it) {  // stage A 128x64
            int e = it * 256 + tid;
            int row = e >> 3, unit = e & 7;
            uint4 v = *(const uint4*)(A + (size_t)(bm * 128 + row) * KVP + kt * 64 + unit * 8);
            *(uint4*)(As + row * 128 + ((unit * 16) ^ ((row & 7) << 4))) = v;
        }
#pragma unroll
        for (int it = 0; it < 2; ++it) {  // stage B 64x64
            int e = it * 256 + tid;
            int row = e >> 3, unit = e & 7;
            uint4 v = *(const uint4*)(Bt + (size_t)(bn * 64 + row) * KVP + kt * 64 + unit * 8);
            *(uint4*)(Bs + row * 128 + ((unit * 16) ^ ((row & 7) << 4))) = v;
        }
        __syncthreads();
#pragma unroll
        for (int ks = 0; ks < 2; ++ks) {
            int colb = ks * 64 + hi * 16;
            bf16x8 a[4], b[2];
#pragma unroll
            for (int km = 0; km < 4; ++km) {
                int arow = wm * 64 + km * 16 + l15;
                a[km] = *(const bf16x8*)(As + arow * 128 + (colb ^ ((arow & 7) << 4)));
            }
#pragma unroll
            for (int ln = 0; ln < 2; ++ln) {
                int brow = wn * 32 + ln * 16 + l15;
                b[ln] = *(const bf16x8*)(Bs + brow * 128 + (colb ^ ((brow & 7) << 4)));
            }
#pragma unroll
            for (int km = 0; km < 4; ++km)
#pragma unroll
                for (int ln = 0; ln < 2; ++ln)
                    acc[km][ln] = __builtin_amdgcn_mfma_f32_16x16x32_bf16(a[km], b[ln], acc[km][ln], 0, 0, 0);
        }
        __syncthreads();
    }
#pragma unroll
    for (int km = 0; km < 4; ++km)
#pragma unroll
        for (int ln = 0; ln < 2; ++ln)
#pragma unroll
            for (int r = 0; r < 4; ++r) {
                int row = bm * 128 + wm * 64 + km * 16 + hi * 4 + r;
                int col = bn * 64 + wn * 32 + ln * 16 + l15;
                float x = acc[km][ln][r] + b1[col];
                float g = 0.5f * x * (1.f + erff(x * 0.70710678118654752f));
                Hout[(size_t)row * H1 + col] = f2bf(g);
            }
}

// ---------------- GEMM2: (6144 x 384) @ w2t^T (256 x 384) + b2 -> out fp32 ---
__global__ __launch_bounds__(256) void k_gemm2(const unsigned short* __restrict__ A,
                                               const unsigned short* __restrict__ Bt,
                                               const float* __restrict__ b2,
                                               float* __restrict__ outp, int lvl) {
    __shared__ uint4 As4[512];  // 64 x 128B
    __shared__ uint4 Bs4[512];
    unsigned char* As = (unsigned char*)As4;
    unsigned char* Bs = (unsigned char*)Bs4;
    int bm = blockIdx.x % 96, bn = blockIdx.x / 96;
    int tid = threadIdx.x, lane = tid & 63;
    int wid = tid >> 6, wm = wid & 1, wn = wid >> 1;
    int l15 = lane & 15, hi = lane >> 4;
    f32x4 acc[2][2] = {};
    const int KT = H1 / 64;  // 6
    for (int kt = 0; kt < KT; ++kt) {
#pragma unroll
        for (int it = 0; it < 2; ++it) {  // stage A 64x64
            int e = it * 256 + tid;
            int row = e >> 3, unit = e & 7;
            uint4 v = *(const uint4*)(A + (size_t)(bm * 64 + row) * H1 + kt * 64 + unit * 8);
            *(uint4*)(As + row * 128 + ((unit * 16) ^ ((row & 7) << 4))) = v;
        }
#pragma unroll
        for (int it = 0; it < 2; ++it) {  // stage B 64x64
            int e = it * 256 + tid;
            int row = e >> 3, unit = e & 7;
            uint4 v = *(const uint4*)(Bt + (size_t)(bn * 64 + row) * H1 + kt * 64 + unit * 8);
            *(uint4*)(Bs + row * 128 + ((unit * 16) ^ ((row & 7) << 4))) = v;
        }
        __syncthreads();
#pragma unroll
        for (int ks = 0; ks < 2; ++ks) {
            int colb = ks * 64 + hi * 16;
            bf16x8 a[2], b[2];
#pragma unroll
            for (int km = 0; km < 2; ++km) {
                int arow = wm * 32 + km * 16 + l15;
                a[km] = *(const bf16x8*)(As + arow * 128 + (colb ^ ((arow & 7) << 4)));
            }
#pragma unroll
            for (int ln = 0; ln < 2; ++ln) {
                int brow = wn * 32 + ln * 16 + l15;
                b[ln] = *(const bf16x8*)(Bs + brow * 128 + (colb ^ ((brow & 7) << 4)));
            }
#pragma unroll
            for (int km = 0; km < 2; ++km)
#pragma unroll
                for (int ln = 0; ln < 2; ++ln)
                    acc[km][ln] = __builtin_amdgcn_mfma_f32_16x16x32_bf16(a[km], b[ln], acc[km][ln], 0, 0, 0);
        }
        __syncthreads();
    }
#pragma unroll
    for (int km = 0; km < 2; ++km)
#pragma unroll
        for (int ln = 0; ln < 2; ++ln)
#pragma unroll
            for (int r = 0; r < 4; ++r) {
                int row = bm * 64 + wm * 32 + km * 16 + hi * 4 + r;
                int col = bn * 64 + wn * 32 + ln * 16 + l15;
                outp[(size_t)row * (4 * OUTC) + lvl * OUTC + col] = acc[km][ln][r] + b2[col];
            }
}

extern "C" void kernel_launch(void* const* d_in, const int* in_sizes, int n_in,
                              void* d_out, int out_size, void* d_ws, size_t ws_size,
                              hipStream_t stream) {
    const float* fmaps   = (const float*)d_in[0];
    const float* coords  = (const float*)d_in[1];
    const float* qcoords = (const float*)d_in[2];
    const int*   qframes = (const int*)d_in[3];
    const float* w1      = (const float*)d_in[4];
    const float* b1      = (const float*)d_in[5];
    const float* w2      = (const float*)d_in[6];
    const float* b2      = (const float*)d_in[7];
    float* outp = (float*)d_out;

    unsigned char* ws = (unsigned char*)d_ws;
    size_t off = 0;
    auto take = [&](size_t bytes) {
        unsigned char* p = ws + off;
        off += (bytes + 255) & ~(size_t)255;
        return p;
    };
    unsigned short* fm0  = (unsigned short*)take((size_t)T_ * H_ * W_ * D_ * 2);
    unsigned short* fm1  = (unsigned short*)take((size_t)T_ * 48 * 64 * D_ * 2);
    unsigned short* fm2  = (unsigned short*)take((size_t)T_ * 24 * 32 * D_ * 2);
    unsigned short* fm3  = (unsigned short*)take((size_t)T_ * 12 * 16 * D_ * 2);
    unsigned short* tfg  = (unsigned short*)take((size_t)N_ * 64 * D_ * 2);
    unsigned short* vol  = (unsigned short*)take((size_t)T_ * N_ * KVP * 2);
    unsigned short* hbuf = (unsigned short*)take((size_t)T_ * N_ * H1 * 2);
    unsigned short* w1t  = (unsigned short*)take((size_t)H1 * KVP * 2);
    unsigned short* w2t  = (unsigned short*)take((size_t)OUTC * H1 * 2);

    hipLaunchKernelGGL(k_w1t, dim3((H1 * KVP + 255) / 256), dim3(256), 0, stream, w1, w1t);
    hipLaunchKernelGGL(k_w2t, dim3((OUTC * H1 + 255) / 256), dim3(256), 0, stream, w2, w2t);
    hipLaunchKernelGGL(k_normalize, dim3(T_ * H_), dim3(256), 0, stream, fmaps, fm0);
    hipLaunchKernelGGL(k_pool, dim3((T_ * 48 * 64 * 32 + 255) / 256), dim3(256), 0, stream, fm0, fm1, 96, 128);
    hipLaunchKernelGGL(k_pool, dim3((T_ * 24 * 32 * 32 + 255) / 256), dim3(256), 0, stream, fm1, fm2, 48, 64);
    hipLaunchKernelGGL(k_pool, dim3((T_ * 12 * 16 * 32 + 255) / 256), dim3(256), 0, stream, fm2, fm3, 24, 32);

    unsigned short* fms[4] = {fm0, fm1, fm2, fm3};
    int Hs[4] = {96, 48, 24, 12}, Wss[4] = {128, 64, 32, 16};
    float invs[4] = {1.f, 0.5f, 0.25f, 0.125f};
    for (int lvl = 0; lvl < 4; ++lvl) {
        hipLaunchKernelGGL(k_tf, dim3(N_), dim3(256), 0, stream,
                           fms[lvl], qcoords, qframes, tfg, Hs[lvl], Wss[lvl], invs[lvl]);
        hipLaunchKernelGGL(k_cfvol, dim3(T_ * N_), dim3(256), 0, stream,
                           fms[lvl], coords, tfg, vol, Hs[lvl], Wss[lvl], invs[lvl]);
        hipLaunchKernelGGL(k_gemm1, dim3(48 * 6), dim3(256), 0, stream, vol, w1t, b1, hbuf);
        hipLaunchKernelGGL(k_gemm2, dim3(96 * 4), dim3(256), 0, stream, hbuf, w2t, b2, outp, lvl);
    }
}

// Round 2
// 371.812 us; speedup vs baseline: 1.4177x; 1.4177x over previous
//
#include <hip/hip_runtime.h>
#include <hip/hip_bf16.h>
#include <stdint.h>

// Problem constants (fixed by setup_inputs)
#define T_   24
#define D_   128
#define H_   96
#define W_   128
#define N_   256
#define KP   49      // 7x7 support points
#define KV   2401    // 49*49
#define KVP  2432    // padded to multiple of 64
#define H1   384     // MLP hidden
#define OUTC 256     // MLP out
#define MTOT (4 * T_ * N_)   // 24576 rows batched over levels

typedef __attribute__((ext_vector_type(8))) __bf16 bf16x8;
typedef __attribute__((ext_vector_type(4))) float f32x4;

typedef __attribute__((address_space(3))) unsigned int lds_u32;
typedef const __attribute__((address_space(1))) unsigned int g_u32;
#define GLOAD16(g, l) __builtin_amdgcn_global_load_lds((g_u32*)(g), (lds_u32*)(l), 16, 0, 0)

__device__ inline float bf2f(unsigned short u) {
    union { unsigned int i; float f; } v; v.i = ((unsigned int)u) << 16; return v.f;
}
__device__ inline unsigned short f2bf(float f) {
    union { float f; unsigned int i; } v; v.f = f;
    unsigned int i = v.i;
    return (unsigned short)((i + 0x7FFFu + ((i >> 16) & 1u)) >> 16);  // RNE
}

// ---------------- weight transpose/convert (one-time per call) ----------------
__global__ __launch_bounds__(256) void k_w1t(const float* __restrict__ w1,
                                             unsigned short* __restrict__ w1t) {
    int idx = blockIdx.x * 256 + threadIdx.x;           // H1*KVP
    if (idx >= H1 * KVP) return;
    int n = idx / KVP, k = idx % KVP;
    float v = (k < KV) ? w1[(size_t)k * H1 + n] : 0.f;
    w1t[idx] = f2bf(v);
}
__global__ __launch_bounds__(256) void k_w2t(const float* __restrict__ w2,
                                             unsigned short* __restrict__ w2t) {
    int idx = blockIdx.x * 256 + threadIdx.x;           // OUTC*H1
    if (idx >= OUTC * H1) return;
    int j = idx / H1, k = idx % H1;
    w2t[idx] = f2bf(w2[(size_t)k * OUTC + j]);
}

// ---------------- L2 normalize + transpose (T,D,H,W)f32 -> (T,H,W,D)bf16 -----
__global__ __launch_bounds__(256) void k_normalize(const float* __restrict__ fmaps,
                                                   unsigned short* __restrict__ fm0) {
    int bid = blockIdx.x;                 // t*H_ + h
    int t = bid / H_, h = bid % H_;
    int tid = threadIdx.x;
    __shared__ float ssum[256];
    __shared__ float rs[W_];
    __shared__ float tile[64 * 129];
    const float* base = fmaps + (size_t)t * D_ * H_ * W_ + (size_t)h * W_;
    {   // sum of squares per w (reads coalesced in w)
        int w = tid & 127, half = tid >> 7;
        float ss = 0.f;
        for (int d = half * 64; d < half * 64 + 64; ++d) {
            float v = base[(size_t)d * (H_ * W_) + w];
            ss += v * v;
        }
        ssum[tid] = ss;
    }
    __syncthreads();
    if (tid < W_) rs[tid] = rsqrtf(fmaxf(ssum[tid] + ssum[tid + 128], 1e-12f));
    __syncthreads();
    unsigned short* orow = fm0 + (size_t)(t * H_ + h) * (W_ * D_);
    for (int wt = 0; wt < 2; ++wt) {      // transpose 64-w tiles through LDS
        int wl = tid & 63, dg = tid >> 6;
        int w = wt * 64 + wl;
        float r = rs[w];
        for (int d = dg * 32; d < dg * 32 + 32; ++d)
            tile[wl * 129 + d] = base[(size_t)d * (H_ * W_) + w] * r;
        __syncthreads();
        int d2 = tid & 127, wh = tid >> 7;
        for (int i = 0; i < 32; ++i) {
            int wll = wh * 32 + i;
            orow[(size_t)(wt * 64 + wll) * D_ + d2] = f2bf(tile[wll * 129 + d2]);
        }
        __syncthreads();
    }
}

// ---------------- 2x2 avg pool, bf16 in/out, fp32 accum ----------------------
__global__ __launch_bounds__(256) void k_pool(const unsigned short* __restrict__ in,
                                              unsigned short* __restrict__ out,
                                              int Hs, int Ws) {
    int Ho = Hs >> 1, Wo = Ws >> 1;
    size_t total = (size_t)T_ * Ho * Wo * (D_ / 4);
    size_t idx = (size_t)blockIdx.x * 256 + threadIdx.x;
    if (idx >= total) return;
    int d4 = idx & 31;
    size_t p = idx >> 5;
    int x = (int)(p % Wo); p /= Wo;
    int y = (int)(p % Ho); int t = (int)(p / Ho);
    const unsigned short* b0 = in + (((size_t)t * Hs + 2 * y) * Ws + 2 * x) * D_ + d4 * 4;
    const unsigned short* b1r = b0 + (size_t)Ws * D_;
    float acc[4] = {0.f, 0.f, 0.f, 0.f};
#pragma unroll
    for (int j = 0; j < 2; ++j) {
        const unsigned short* bb = j ? b1r : b0;
#pragma unroll
        for (int i = 0; i < 2; ++i) {
            const unsigned short* q = bb + i * D_;
#pragma unroll
            for (int c = 0; c < 4; ++c) acc[c] += bf2f(q[c]);
        }
    }
    unsigned short* o = out + (((size_t)t * Ho + y) * Wo + x) * D_ + d4 * 4;
#pragma unroll
    for (int c = 0; c < 4; ++c) o[c] = f2bf(acc[c] * 0.25f);
}

// ---------------- bilinear sampler: 2 channels per lane ----------------------
__device__ inline float2 bilin2(const unsigned short* __restrict__ fb, int Hs, int Ws,
                                float px, float py, int lane) {
    float x0f = floorf(px), y0f = floorf(py);
    float tx = px - x0f, ty = py - y0f;
    int x0 = (int)x0f, y0 = (int)y0f;
    float acc0 = 0.f, acc1 = 0.f;
#pragma unroll
    for (int dy = 0; dy < 2; ++dy) {
#pragma unroll
        for (int dx = 0; dx < 2; ++dx) {
            int xi = x0 + dx, yi = y0 + dy;
            float w = (dx ? tx : 1.f - tx) * (dy ? ty : 1.f - ty);
            bool valid = (xi >= 0) && (xi < Ws) && (yi >= 0) && (yi < Hs);
            int xc = xi < 0 ? 0 : (xi > Ws - 1 ? Ws - 1 : xi);
            int yc = yi < 0 ? 0 : (yi > Hs - 1 ? Hs - 1 : yi);
            unsigned int pk = *(const unsigned int*)(fb + ((size_t)yc * Ws + xc) * D_ + lane * 2);
            float wv = valid ? w : 0.f;
            acc0 += wv * bf2f((unsigned short)(pk & 0xffffu));
            acc1 += wv * bf2f((unsigned short)(pk >> 16));
        }
    }
    return {acc0, acc1};
}

// ---------------- track-support features, all levels: (4,N,64,128) bf16 ------
__global__ __launch_bounds__(256) void k_tf(const unsigned short* __restrict__ fm0,
                                            const unsigned short* __restrict__ fm1,
                                            const unsigned short* __restrict__ fm2,
                                            const unsigned short* __restrict__ fm3,
                                            const float* __restrict__ qcoords,
                                            const int* __restrict__ qframes,
                                            unsigned short* __restrict__ tfg) {
    int n = blockIdx.x, lvl = blockIdx.y;
    const unsigned short* fm = lvl == 0 ? fm0 : lvl == 1 ? fm1 : lvl == 2 ? fm2 : fm3;
    int Hs = H_ >> lvl, Ws = W_ >> lvl;
    float inv = 1.0f / (float)(1 << lvl);
    int wid = threadIdx.x >> 6, lane = threadIdx.x & 63;
    int fidx = qframes[n];
    float qx = qcoords[n * 2 + 0] * inv, qy = qcoords[n * 2 + 1] * inv;
    const unsigned short* fb = fm + (size_t)fidx * Hs * Ws * D_;
    unsigned short* orow = tfg + ((size_t)lvl * N_ + n) * (64 * D_);
    for (int k = wid; k < 64; k += 4) {
        float2 v = {0.f, 0.f};
        if (k < KP) {
            float px = qx + (float)(k / 7 - 3);
            float py = qy + (float)(k % 7 - 3);
            v = bilin2(fb, Hs, Ws, px, py, lane);
        }
        unsigned int pk = (unsigned int)f2bf(v.x) | ((unsigned int)f2bf(v.y) << 16);
        *(unsigned int*)(orow + k * D_ + lane * 2) = pk;
    }
}

// ---------------- cf + 49x49 correlation via shared 8x8 patch ---------------
// All 49 support points share one fractional offset -> load the 8x8 integer
// pixel patch P once, G = P . tf^T via MFMA, then vol[k,l] = 4-tap combine of
// G rows. Block = (n, t-group of 6, lvl). 3 barriers per t.
__global__ __launch_bounds__(256) void k_cfvol(const unsigned short* __restrict__ fm0,
                                               const unsigned short* __restrict__ fm1,
                                               const unsigned short* __restrict__ fm2,
                                               const unsigned short* __restrict__ fm3,
                                               const float* __restrict__ coords,
                                               const unsigned short* __restrict__ tfg,
                                               unsigned short* __restrict__ vol) {
    __shared__ unsigned char tfs[16384];
    __shared__ unsigned char Ps[16384];
    __shared__ float Gs[64 * 68];    // row stride 68 floats: conflict-free
    int n = blockIdx.x, tg = blockIdx.y, lvl = blockIdx.z;
    const unsigned short* fm = lvl == 0 ? fm0 : lvl == 1 ? fm1 : lvl == 2 ? fm2 : fm3;
    int Hs = H_ >> lvl, Ws = W_ >> lvl;
    float inv = 1.0f / (float)(1 << lvl);
    int tid = threadIdx.x, wid = tid >> 6, lane = tid & 63;
    int l15 = lane & 15, hi = lane >> 4;
    // stage tf once (swizzled); first in-loop barrier covers it
    const unsigned short* tfn = tfg + ((size_t)lvl * N_ + n) * (64 * D_);
#pragma unroll
    for (int it = 0; it < 4; ++it) {
        int e = it * 256 + tid;
        int row = e >> 4, unit = e & 15;
        uint4 v = *(const uint4*)(tfn + row * 128 + unit * 8);
        *(uint4*)(tfs + row * 256 + ((unit * 16) ^ ((row & 7) << 4))) = v;
    }
    for (int ti = 0; ti < 6; ++ti) {
        int t = tg * 6 + ti;
        float cx = coords[((size_t)t * N_ + n) * 2 + 0] * inv;
        float cy = coords[((size_t)t * N_ + n) * 2 + 1] * inv;
        float fx = floorf(cx), fy = floorf(cy);
        float tx = cx - fx, ty = cy - fy;
        int bx = (int)fx - 3, by = (int)fy - 3;
        // stage P: pixel (a,b) -> row a*8+b (a = x index, b = y index)
#pragma unroll
        for (int it = 0; it < 4; ++it) {
            int e = it * 256 + tid;
            int row = e >> 4, unit = e & 15;
            int a = row >> 3, b = row & 7;
            int x = bx + a, y = by + b;
            bool valid = (x >= 0) && (x < Ws) && (y >= 0) && (y < Hs);
            uint4 v = {0u, 0u, 0u, 0u};
            if (valid)
                v = *(const uint4*)(fm + ((size_t)t * Hs * Ws + (size_t)y * Ws + x) * D_ + unit * 8);
            *(uint4*)(Ps + row * 256 + ((unit * 16) ^ ((row & 7) << 4))) = v;
        }
        __syncthreads();
        // G = P . tf^T : wave wid computes G rows [wid*16, wid*16+16)
        f32x4 acc[4] = {f32x4{0,0,0,0}, f32x4{0,0,0,0}, f32x4{0,0,0,0}, f32x4{0,0,0,0}};
#pragma unroll
        for (int ks = 0; ks < 4; ++ks) {
            int colb = ks * 64 + hi * 16;
            int arow = wid * 16 + l15;
            bf16x8 a = *(const bf16x8*)(Ps + arow * 256 + (colb ^ ((arow & 7) << 4)));
#pragma unroll
            for (int ln = 0; ln < 4; ++ln) {
                int brow = ln * 16 + l15;
                bf16x8 b = *(const bf16x8*)(tfs + brow * 256 + (colb ^ ((brow & 7) << 4)));
                acc[ln] = __builtin_amdgcn_mfma_f32_16x16x32_bf16(a, b, acc[ln], 0, 0, 0);
            }
        }
#pragma unroll
        for (int ln = 0; ln < 4; ++ln)
#pragma unroll
            for (int r = 0; r < 4; ++r)
                Gs[(wid * 16 + hi * 4 + r) * 68 + ln * 16 + l15] = acc[ln][r];
        __syncthreads();
        // combine: vol[k,l] = w00*G[g]+w01*G[g+1]+w10*G[g+8]+w11*G[g+9]
        unsigned short* vrow = vol + (((size_t)lvl * T_ + t) * N_ + n) * KVP;
        float w00 = (1.f - tx) * (1.f - ty), w01 = (1.f - tx) * ty;
        float w10 = tx * (1.f - ty), w11 = tx * ty;
        int l = lane;
        for (int k = wid; k < KP; k += 4) {
            int a0 = k / 7, b0 = k % 7;
            int g = a0 * 8 + b0;
            float v = w00 * Gs[g * 68 + l] + w01 * Gs[(g + 1) * 68 + l]
                    + w10 * Gs[(g + 8) * 68 + l] + w11 * Gs[(g + 9) * 68 + l];
            if (l < KP) vrow[k * KP + l] = f2bf(v);
        }
        if (tid < KVP - KV) vrow[KV + tid] = 0;  // zero pad cols
        __syncthreads();
    }
}

// ---------------- GEMM1 (batched levels): (24576 x KVP) @ w1t^T (384 x KVP) --
// m97 structure: BM=128, BN=128, BK=64, global_load_lds width=16 with
// pre-swizzled global source (linear LDS dest, XOR on ds_read).
__global__ __launch_bounds__(256) void k_gemm1(const unsigned short* __restrict__ A,
                                               const unsigned short* __restrict__ Bt,
                                               const float* __restrict__ b1,
                                               unsigned short* __restrict__ Hout) {
    __shared__ unsigned char As[16384];   // 128 rows x 128B, swizzled content
    __shared__ unsigned char Bs[16384];
    int bm = blockIdx.x % (MTOT / 128), bn = blockIdx.x / (MTOT / 128);
    int tid = threadIdx.x, lane = tid & 63;
    int wid = tid >> 6, wm = wid & 1, wn = wid >> 1;
    int l15 = lane & 15, hi = lane >> 4;
    f32x4 acc[4][4] = {};
    const unsigned short* Abase = A + (size_t)(bm * 128) * KVP;
    const unsigned short* Bbase = Bt + (size_t)(bn * 128) * KVP;
    // per-lane staging geometry: e = (wid*4+q)*64 + lane; row = e>>3, unit = e&7
    int e0 = wid * 4 * 64 + lane;
    for (int kt = 0; kt < KVP / 64; ++kt) {
#pragma unroll
        for (int q = 0; q < 4; ++q) {
            int e = e0 + q * 64;
            int row = e >> 3, su = (e & 7) ^ (row & 7);
            GLOAD16(Abase + (size_t)row * KVP + kt * 64 + su * 8, As + (wid * 4 + q) * 1024);
        }
#pragma unroll
        for (int q = 0; q < 4; ++q) {
            int e = e0 + q * 64;
            int row = e >> 3, su = (e & 7) ^ (row & 7);
            GLOAD16(Bbase + (size_t)row * KVP + kt * 64 + su * 8, Bs + (wid * 4 + q) * 1024);
        }
        __syncthreads();
#pragma unroll
        for (int ks = 0; ks < 2; ++ks) {
            int colb = ks * 64 + hi * 16;
            bf16x8 a[4], b[4];
#pragma unroll
            for (int km = 0; km < 4; ++km) {
                int arow = wm * 64 + km * 16 + l15;
                a[km] = *(const bf16x8*)(As + arow * 128 + (colb ^ ((arow & 7) << 4)));
            }
#pragma unroll
            for (int ln = 0; ln < 4; ++ln) {
                int brow = wn * 64 + ln * 16 + l15;
                b[ln] = *(const bf16x8*)(Bs + brow * 128 + (colb ^ ((brow & 7) << 4)));
            }
#pragma unroll
            for (int km = 0; km < 4; ++km)
#pragma unroll
                for (int ln = 0; ln < 4; ++ln)
                    acc[km][ln] = __builtin_amdgcn_mfma_f32_16x16x32_bf16(a[km], b[ln], acc[km][ln], 0, 0, 0);
        }
        __syncthreads();
    }
#pragma unroll
    for (int km = 0; km < 4; ++km)
#pragma unroll
        for (int ln = 0; ln < 4; ++ln)
#pragma unroll
            for (int r = 0; r < 4; ++r) {
                int row = bm * 128 + wm * 64 + km * 16 + hi * 4 + r;
                int col = bn * 128 + wn * 64 + ln * 16 + l15;
                float x = acc[km][ln][r] + b1[col];
                float g = 0.5f * x * (1.f + erff(x * 0.70710678118654752f));
                Hout[(size_t)row * H1 + col] = f2bf(g);
            }
}

// ---------------- GEMM2 (batched): (24576 x 384) @ w2t^T (256 x 384) ---------
__global__ __launch_bounds__(256) void k_gemm2(const unsigned short* __restrict__ A,
                                               const unsigned short* __restrict__ Bt,
                                               const float* __restrict__ b2,
                                               float* __restrict__ outp) {
    __shared__ unsigned char As[16384];   // 128 x 128B
    __shared__ unsigned char Bs[8192];    // 64 x 128B
    int bm = blockIdx.x % (MTOT / 128), bn = blockIdx.x / (MTOT / 128);
    int tid = threadIdx.x, lane = tid & 63;
    int wid = tid >> 6, wm = wid & 1, wn = wid >> 1;
    int l15 = lane & 15, hi = lane >> 4;
    f32x4 acc[4][2] = {};
    const unsigned short* Abase = A + (size_t)(bm * 128) * H1;
    const unsigned short* Bbase = Bt + (size_t)(bn * 64) * H1;
    for (int kt = 0; kt < H1 / 64; ++kt) {
#pragma unroll
        for (int q = 0; q < 4; ++q) {
            int e = (wid * 4 + q) * 64 + lane;
            int row = e >> 3, su = (e & 7) ^ (row & 7);
            GLOAD16(Abase + (size_t)row * H1 + kt * 64 + su * 8, As + (wid * 4 + q) * 1024);
        }
#pragma unroll
        for (int q = 0; q < 2; ++q) {
            int e = (wid * 2 + q) * 64 + lane;
            int row = e >> 3, su = (e & 7) ^ (row & 7);
            GLOAD16(Bbase + (size_t)row * H1 + kt * 64 + su * 8, Bs + (wid * 2 + q) * 1024);
        }
        __syncthreads();
#pragma unroll
        for (int ks = 0; ks < 2; ++ks) {
            int colb = ks * 64 + hi * 16;
            bf16x8 a[4], b[2];
#pragma unroll
            for (int km = 0; km < 4; ++km) {
                int arow = wm * 64 + km * 16 + l15;
                a[km] = *(const bf16x8*)(As + arow * 128 + (colb ^ ((arow & 7) << 4)));
            }
#pragma unroll
            for (int ln = 0; ln < 2; ++ln) {
                int brow = wn * 32 + ln * 16 + l15;
                b[ln] = *(const bf16x8*)(Bs + brow * 128 + (colb ^ ((brow & 7) << 4)));
            }
#pragma unroll
            for (int km = 0; km < 4; ++km)
#pragma unroll
                for (int ln = 0; ln < 2; ++ln)
                    acc[km][ln] = __builtin_amdgcn_mfma_f32_16x16x32_bf16(a[km], b[ln], acc[km][ln], 0, 0, 0);
        }
        __syncthreads();
    }
#pragma unroll
    for (int km = 0; km < 4; ++km)
#pragma unroll
        for (int ln = 0; ln < 2; ++ln)
#pragma unroll
            for (int r = 0; r < 4; ++r) {
                int row = bm * 128 + wm * 64 + km * 16 + hi * 4 + r;
                int col = bn * 64 + wn * 32 + ln * 16 + l15;
                int lvl = row / (T_ * N_);
                int r2 = row - lvl * (T_ * N_);
                outp[(size_t)r2 * (4 * OUTC) + lvl * OUTC + col] = acc[km][ln][r] + b2[col];
            }
}

extern "C" void kernel_launch(void* const* d_in, const int* in_sizes, int n_in,
                              void* d_out, int out_size, void* d_ws, size_t ws_size,
                              hipStream_t stream) {
    const float* fmaps   = (const float*)d_in[0];
    const float* coords  = (const float*)d_in[1];
    const float* qcoords = (const float*)d_in[2];
    const int*   qframes = (const int*)d_in[3];
    const float* w1      = (const float*)d_in[4];
    const float* b1      = (const float*)d_in[5];
    const float* w2      = (const float*)d_in[6];
    const float* b2      = (const float*)d_in[7];
    float* outp = (float*)d_out;

    unsigned char* ws = (unsigned char*)d_ws;
    size_t off = 0;
    auto take = [&](size_t bytes) {
        unsigned char* p = ws + off;
        off += (bytes + 255) & ~(size_t)255;
        return p;
    };
    unsigned short* fm0  = (unsigned short*)take((size_t)T_ * H_ * W_ * D_ * 2);
    unsigned short* fm1  = (unsigned short*)take((size_t)T_ * 48 * 64 * D_ * 2);
    unsigned short* fm2  = (unsigned short*)take((size_t)T_ * 24 * 32 * D_ * 2);
    unsigned short* fm3  = (unsigned short*)take((size_t)T_ * 12 * 16 * D_ * 2);
    unsigned short* tfg  = (unsigned short*)take((size_t)4 * N_ * 64 * D_ * 2);
    unsigned short* vol  = (unsigned short*)take((size_t)MTOT * KVP * 2);
    unsigned short* hbuf = (unsigned short*)take((size_t)MTOT * H1 * 2);
    unsigned short* w1t  = (unsigned short*)take((size_t)H1 * KVP * 2);
    unsigned short* w2t  = (unsigned short*)take((size_t)OUTC * H1 * 2);

    hipLaunchKernelGGL(k_w1t, dim3((H1 * KVP + 255) / 256), dim3(256), 0, stream, w1, w1t);
    hipLaunchKernelGGL(k_w2t, dim3((OUTC * H1 + 255) / 256), dim3(256), 0, stream, w2, w2t);
    hipLaunchKernelGGL(k_normalize, dim3(T_ * H_), dim3(256), 0, stream, fmaps, fm0);
    hipLaunchKernelGGL(k_pool, dim3((T_ * 48 * 64 * 32 + 255) / 256), dim3(256), 0, stream, fm0, fm1, 96, 128);
    hipLaunchKernelGGL(k_pool, dim3((T_ * 24 * 32 * 32 + 255) / 256), dim3(256), 0, stream, fm1, fm2, 48, 64);
    hipLaunchKernelGGL(k_pool, dim3((T_ * 12 * 16 * 32 + 255) / 256), dim3(256), 0, stream, fm2, fm3, 24, 32);

    hipLaunchKernelGGL(k_tf, dim3(N_, 4), dim3(256), 0, stream,
                       fm0, fm1, fm2, fm3, qcoords, qframes, tfg);
    hipLaunchKernelGGL(k_cfvol, dim3(N_, 4, 4), dim3(256), 0, stream,
                       fm0, fm1, fm2, fm3, coords, tfg, vol);
    hipLaunchKernelGGL(k_gemm1, dim3((MTOT / 128) * 3), dim3(256), 0, stream, vol, w1t, b1, hbuf);
    hipLaunchKernelGGL(k_gemm2, dim3((MTOT / 128) * 4), dim3(256), 0, stream, hbuf, w2t, b2, outp);
}

// Round 3
// 362.468 us; speedup vs baseline: 1.4543x; 1.0258x over previous
//
#include <hip/hip_runtime.h>
#include <hip/hip_bf16.h>
#include <stdint.h>

// Problem constants (fixed by setup_inputs)
#define T_   24
#define D_   128
#define H_   96
#define W_   128
#define N_   256
#define KP   49      // 7x7 support points
#define K2   3136    // vol K-dim: 49 k-rows x 64 l-slots (l>=49 zero-padded)
#define H1   384     // MLP hidden
#define OUTC 256     // MLP out
#define MTOT (4 * T_ * N_)   // 24576 rows batched over levels

typedef __attribute__((ext_vector_type(8))) __bf16 bf16x8;
typedef __attribute__((ext_vector_type(4))) float f32x4;

typedef __attribute__((address_space(3))) unsigned int lds_u32;
typedef const __attribute__((address_space(1))) unsigned int g_u32;
#define GLOAD16(g, l) __builtin_amdgcn_global_load_lds((g_u32*)(g), (lds_u32*)(l), 16, 0, 0)

__device__ inline float bf2f(unsigned short u) {
    union { unsigned int i; float f; } v; v.i = ((unsigned int)u) << 16; return v.f;
}
__device__ inline unsigned short f2bf(float f) {
    union { float f; unsigned int i; } v; v.f = f;
    unsigned int i = v.i;
    return (unsigned short)((i + 0x7FFFu + ((i >> 16) & 1u)) >> 16);  // RNE
}

// ---------------- weight transpose/convert (one-time per call) ----------------
// w1t layout: [n][k*64 + l], l>=49 zero (matches vol layout)
__global__ __launch_bounds__(256) void k_w1t(const float* __restrict__ w1,
                                             unsigned short* __restrict__ w1t) {
    int idx = blockIdx.x * 256 + threadIdx.x;           // H1*K2
    if (idx >= H1 * K2) return;
    int nn = idx / K2, kk = idx % K2;
    int k = kk >> 6, l = kk & 63;
    float v = (l < KP) ? w1[((size_t)k * KP + l) * H1 + nn] : 0.f;
    w1t[idx] = f2bf(v);
}
__global__ __launch_bounds__(256) void k_w2t(const float* __restrict__ w2,
                                             unsigned short* __restrict__ w2t) {
    int idx = blockIdx.x * 256 + threadIdx.x;           // OUTC*H1
    if (idx >= OUTC * H1) return;
    int j = idx / H1, k = idx % H1;
    w2t[idx] = f2bf(w2[(size_t)k * OUTC + j]);
}

// ---------------- L2 normalize + transpose (T,D,H,W)f32 -> (T,H,W,D)bf16 -----
__global__ __launch_bounds__(256) void k_normalize(const float* __restrict__ fmaps,
                                                   unsigned short* __restrict__ fm0) {
    int bid = blockIdx.x;                 // t*H_ + h
    int t = bid / H_, h = bid % H_;
    int tid = threadIdx.x;
    __shared__ float ssum[256];
    __shared__ float rs[W_];
    __shared__ float tile[64 * 129];
    const float* base = fmaps + (size_t)t * D_ * H_ * W_ + (size_t)h * W_;
    {   // sum of squares per w (reads coalesced in w)
        int w = tid & 127, half = tid >> 7;
        float ss = 0.f;
        for (int d = half * 64; d < half * 64 + 64; ++d) {
            float v = base[(size_t)d * (H_ * W_) + w];
            ss += v * v;
        }
        ssum[tid] = ss;
    }
    __syncthreads();
    if (tid < W_) rs[tid] = rsqrtf(fmaxf(ssum[tid] + ssum[tid + 128], 1e-12f));
    __syncthreads();
    unsigned short* orow = fm0 + (size_t)(t * H_ + h) * (W_ * D_);
    for (int wt = 0; wt < 2; ++wt) {      // transpose 64-w tiles through LDS
        int wl = tid & 63, dg = tid >> 6;
        int w = wt * 64 + wl;
        float r = rs[w];
        for (int d = dg * 32; d < dg * 32 + 32; ++d)
            tile[wl * 129 + d] = base[(size_t)d * (H_ * W_) + w] * r;
        __syncthreads();
        int d2 = tid & 127, wh = tid >> 7;
        for (int i = 0; i < 32; ++i) {
            int wll = wh * 32 + i;
            orow[(size_t)(wt * 64 + wll) * D_ + d2] = f2bf(tile[wll * 129 + d2]);
        }
        __syncthreads();
    }
}

// ---------------- 2x2 avg pool, bf16 in/out, fp32 accum ----------------------
__global__ __launch_bounds__(256) void k_pool(const unsigned short* __restrict__ in,
                                              unsigned short* __restrict__ out,
                                              int Hs, int Ws) {
    int Ho = Hs >> 1, Wo = Ws >> 1;
    size_t total = (size_t)T_ * Ho * Wo * (D_ / 4);
    size_t idx = (size_t)blockIdx.x * 256 + threadIdx.x;
    if (idx >= total) return;
    int d4 = idx & 31;
    size_t p = idx >> 5;
    int x = (int)(p % Wo); p /= Wo;
    int y = (int)(p % Ho); int t = (int)(p / Ho);
    const unsigned short* b0 = in + (((size_t)t * Hs + 2 * y) * Ws + 2 * x) * D_ + d4 * 4;
    const unsigned short* b1r = b0 + (size_t)Ws * D_;
    float acc[4] = {0.f, 0.f, 0.f, 0.f};
#pragma unroll
    for (int j = 0; j < 2; ++j) {
        const unsigned short* bb = j ? b1r : b0;
#pragma unroll
        for (int i = 0; i < 2; ++i) {
            const unsigned short* q = bb + i * D_;
#pragma unroll
            for (int c = 0; c < 4; ++c) acc[c] += bf2f(q[c]);
        }
    }
    unsigned short* o = out + (((size_t)t * Ho + y) * Wo + x) * D_ + d4 * 4;
#pragma unroll
    for (int c = 0; c < 4; ++c) o[c] = f2bf(acc[c] * 0.25f);
}

// ---------------- bilinear sampler: 2 channels per lane ----------------------
__device__ inline float2 bilin2(const unsigned short* __restrict__ fb, int Hs, int Ws,
                                float px, float py, int lane) {
    float x0f = floorf(px), y0f = floorf(py);
    float tx = px - x0f, ty = py - y0f;
    int x0 = (int)x0f, y0 = (int)y0f;
    float acc0 = 0.f, acc1 = 0.f;
#pragma unroll
    for (int dy = 0; dy < 2; ++dy) {
#pragma unroll
        for (int dx = 0; dx < 2; ++dx) {
            int xi = x0 + dx, yi = y0 + dy;
            float w = (dx ? tx : 1.f - tx) * (dy ? ty : 1.f - ty);
            bool valid = (xi >= 0) && (xi < Ws) && (yi >= 0) && (yi < Hs);
            int xc = xi < 0 ? 0 : (xi > Ws - 1 ? Ws - 1 : xi);
            int yc = yi < 0 ? 0 : (yi > Hs - 1 ? Hs - 1 : yi);
            unsigned int pk = *(const unsigned int*)(fb + ((size_t)yc * Ws + xc) * D_ + lane * 2);
            float wv = valid ? w : 0.f;
            acc0 += wv * bf2f((unsigned short)(pk & 0xffffu));
            acc1 += wv * bf2f((unsigned short)(pk >> 16));
        }
    }
    return {acc0, acc1};
}

// ---------------- track-support features, all levels: (4,N,64,128) bf16 ------
__global__ __launch_bounds__(256) void k_tf(const unsigned short* __restrict__ fm0,
                                            const unsigned short* __restrict__ fm1,
                                            const unsigned short* __restrict__ fm2,
                                            const unsigned short* __restrict__ fm3,
                                            const float* __restrict__ qcoords,
                                            const int* __restrict__ qframes,
                                            unsigned short* __restrict__ tfg) {
    int n = blockIdx.x, lvl = blockIdx.y;
    const unsigned short* fm = lvl == 0 ? fm0 : lvl == 1 ? fm1 : lvl == 2 ? fm2 : fm3;
    int Hs = H_ >> lvl, Ws = W_ >> lvl;
    float inv = 1.0f / (float)(1 << lvl);
    int wid = threadIdx.x >> 6, lane = threadIdx.x & 63;
    int fidx = qframes[n];
    float qx = qcoords[n * 2 + 0] * inv, qy = qcoords[n * 2 + 1] * inv;
    const unsigned short* fb = fm + (size_t)fidx * Hs * Ws * D_;
    unsigned short* orow = tfg + ((size_t)lvl * N_ + n) * (64 * D_);
    for (int k = wid; k < 64; k += 4) {
        float2 v = {0.f, 0.f};
        if (k < KP) {
            float px = qx + (float)(k / 7 - 3);
            float py = qy + (float)(k % 7 - 3);
            v = bilin2(fb, Hs, Ws, px, py, lane);
        }
        unsigned int pk = (unsigned int)f2bf(v.x) | ((unsigned int)f2bf(v.y) << 16);
        *(unsigned int*)(orow + k * D_ + lane * 2) = pk;
    }
}

// ---------------- cf + 49x49 correlation via shared 8x8 patch ---------------
// One block per (n,t,lvl). All 49 support points share one fractional offset:
// load the 8x8 integer pixel patch P once, G = P . tf^T via MFMA (64 MFMAs),
// then vol[k*64+l] = 4-tap combine of G rows, stored coalesced as packed u32.
// 2 barriers per block total.
__global__ __launch_bounds__(256) void k_cfvol(const unsigned short* __restrict__ fm0,
                                               const unsigned short* __restrict__ fm1,
                                               const unsigned short* __restrict__ fm2,
                                               const unsigned short* __restrict__ fm3,
                                               const float* __restrict__ coords,
                                               const unsigned short* __restrict__ tfg,
                                               unsigned short* __restrict__ vol) {
    __shared__ unsigned char tfs[16384];
    __shared__ unsigned char Ps[16384];
    __shared__ float Gs[64 * 68];    // row stride 68 floats
    int n = blockIdx.x, t = blockIdx.y, lvl = blockIdx.z;
    const unsigned short* fm = lvl == 0 ? fm0 : lvl == 1 ? fm1 : lvl == 2 ? fm2 : fm3;
    int Hs = H_ >> lvl, Ws = W_ >> lvl;
    float inv = 1.0f / (float)(1 << lvl);
    int tid = threadIdx.x, wid = tid >> 6, lane = tid & 63;
    int l15 = lane & 15, hi = lane >> 4;

    // stage tf via global_load_lds with pre-swizzled source (rule 21):
    // linear LDS dest, source address carries the inverse XOR swizzle.
    const unsigned short* tfn = tfg + ((size_t)lvl * N_ + n) * (64 * D_);
#pragma unroll
    for (int i = 0; i < 4; ++i) {
        int row = wid * 16 + i * 4 + (lane >> 4);
        int u = (lane & 15) ^ (row & 7);
        GLOAD16(tfn + row * 128 + u * 8, tfs + wid * 4096 + i * 1024 + lane * 16);
    }
    // stage P: reg-load (OOB predicated to zero), then swizzled LDS write
    float cx = coords[((size_t)t * N_ + n) * 2 + 0] * inv;
    float cy = coords[((size_t)t * N_ + n) * 2 + 1] * inv;
    float fx = floorf(cx), fy = floorf(cy);
    float tx = cx - fx, ty = cy - fy;
    int bx = (int)fx - 3, by = (int)fy - 3;
    uint4 pv[4];
#pragma unroll
    for (int it = 0; it < 4; ++it) {
        int e = it * 256 + tid;
        int row = e >> 4, unit = e & 15;
        int a = row >> 3, b = row & 7;
        int x = bx + a, y = by + b;
        bool valid = (x >= 0) && (x < Ws) && (y >= 0) && (y < Hs);
        uint4 v = {0u, 0u, 0u, 0u};
        if (valid)
            v = *(const uint4*)(fm + ((size_t)t * Hs * Ws + (size_t)y * Ws + x) * D_ + unit * 8);
        pv[it] = v;
    }
#pragma unroll
    for (int it = 0; it < 4; ++it) {
        int e = it * 256 + tid;
        int row = e >> 4, unit = e & 15;
        *(uint4*)(Ps + row * 256 + ((unit * 16) ^ ((row & 7) << 4))) = pv[it];
    }
    __syncthreads();
    // G = P . tf^T : wave wid computes G rows [wid*16, wid*16+16)
    f32x4 acc[4] = {f32x4{0,0,0,0}, f32x4{0,0,0,0}, f32x4{0,0,0,0}, f32x4{0,0,0,0}};
#pragma unroll
    for (int ks = 0; ks < 4; ++ks) {
        int colb = ks * 64 + hi * 16;
        int arow = wid * 16 + l15;
        bf16x8 a = *(const bf16x8*)(Ps + arow * 256 + (colb ^ ((arow & 7) << 4)));
#pragma unroll
        for (int ln = 0; ln < 4; ++ln) {
            int brow = ln * 16 + l15;
            bf16x8 b = *(const bf16x8*)(tfs + brow * 256 + (colb ^ ((brow & 7) << 4)));
            acc[ln] = __builtin_amdgcn_mfma_f32_16x16x32_bf16(a, b, acc[ln], 0, 0, 0);
        }
    }
#pragma unroll
    for (int ln = 0; ln < 4; ++ln)
#pragma unroll
        for (int r = 0; r < 4; ++r)
            Gs[(wid * 16 + hi * 4 + r) * 68 + ln * 16 + l15] = acc[ln][r];
    __syncthreads();
    // combine: vol[k*64+l] = w00*G[g,l]+w01*G[g+1,l]+w10*G[g+8,l]+w11*G[g+9,l]
    // wave handles 2 k-rows per pass; lane packs 2 l-values into one u32 store.
    unsigned int* vrow = (unsigned int*)(vol + (((size_t)lvl * T_ + t) * N_ + n) * K2);
    float w00 = (1.f - tx) * (1.f - ty), w01 = (1.f - tx) * ty;
    float w10 = tx * (1.f - ty), w11 = tx * ty;
    int lh = lane >> 5, ll = lane & 31;
#pragma unroll
    for (int p = 0; p < 7; ++p) {
        int k = p * 8 + wid * 2 + lh;
        if (k < KP) {
            int a0 = k / 7, b0 = k - a0 * 7;
            int g = a0 * 8 + b0;
            const float* gp = &Gs[g * 68 + ll * 2];
            float2 v00 = *(const float2*)(gp);
            float2 v01 = *(const float2*)(gp + 68);
            float2 v10 = *(const float2*)(gp + 8 * 68);
            float2 v11 = *(const float2*)(gp + 9 * 68);
            float r0 = w00 * v00.x + w01 * v01.x + w10 * v10.x + w11 * v11.x;
            float r1 = w00 * v00.y + w01 * v01.y + w10 * v10.y + w11 * v11.y;
            vrow[k * 32 + ll] = (unsigned int)f2bf(r0) | ((unsigned int)f2bf(r1) << 16);
        }
    }
}

// ---------------- GEMM1 (batched levels): (24576 x K2) @ w1t^T (384 x K2) ----
// m97 structure: BM=128, BN=128, BK=64, global_load_lds width=16 with
// pre-swizzled global source (linear LDS dest, XOR on ds_read).
__global__ __launch_bounds__(256) void k_gemm1(const unsigned short* __restrict__ A,
                                               const unsigned short* __restrict__ Bt,
                                               const float* __restrict__ b1,
                                               unsigned short* __restrict__ Hout) {
    __shared__ unsigned char As[16384];   // 128 rows x 128B, swizzled content
    __shared__ unsigned char Bs[16384];
    int bm = blockIdx.x % (MTOT / 128), bn = blockIdx.x / (MTOT / 128);
    int tid = threadIdx.x, lane = tid & 63;
    int wid = tid >> 6, wm = wid & 1, wn = wid >> 1;
    int l15 = lane & 15, hi = lane >> 4;
    f32x4 acc[4][4] = {};
    const unsigned short* Abase = A + (size_t)(bm * 128) * K2;
    const unsigned short* Bbase = Bt + (size_t)(bn * 128) * K2;
    int e0 = wid * 4 * 64 + lane;
    for (int kt = 0; kt < K2 / 64; ++kt) {
#pragma unroll
        for (int q = 0; q < 4; ++q) {
            int e = e0 + q * 64;
            int row = e >> 3, su = (e & 7) ^ (row & 7);
            GLOAD16(Abase + (size_t)row * K2 + kt * 64 + su * 8, As + (wid * 4 + q) * 1024);
        }
#pragma unroll
        for (int q = 0; q < 4; ++q) {
            int e = e0 + q * 64;
            int row = e >> 3, su = (e & 7) ^ (row & 7);
            GLOAD16(Bbase + (size_t)row * K2 + kt * 64 + su * 8, Bs + (wid * 4 + q) * 1024);
        }
        __syncthreads();
#pragma unroll
        for (int ks = 0; ks < 2; ++ks) {
            int colb = ks * 64 + hi * 16;
            bf16x8 a[4], b[4];
#pragma unroll
            for (int km = 0; km < 4; ++km) {
                int arow = wm * 64 + km * 16 + l15;
                a[km] = *(const bf16x8*)(As + arow * 128 + (colb ^ ((arow & 7) << 4)));
            }
#pragma unroll
            for (int ln = 0; ln < 4; ++ln) {
                int brow = wn * 64 + ln * 16 + l15;
                b[ln] = *(const bf16x8*)(Bs + brow * 128 + (colb ^ ((brow & 7) << 4)));
            }
#pragma unroll
            for (int km = 0; km < 4; ++km)
#pragma unroll
                for (int ln = 0; ln < 4; ++ln)
                    acc[km][ln] = __builtin_amdgcn_mfma_f32_16x16x32_bf16(a[km], b[ln], acc[km][ln], 0, 0, 0);
        }
        __syncthreads();
    }
#pragma unroll
    for (int km = 0; km < 4; ++km)
#pragma unroll
        for (int ln = 0; ln < 4; ++ln)
#pragma unroll
            for (int r = 0; r < 4; ++r) {
                int row = bm * 128 + wm * 64 + km * 16 + hi * 4 + r;
                int col = bn * 128 + wn * 64 + ln * 16 + l15;
                float x = acc[km][ln][r] + b1[col];
                float g = 0.5f * x * (1.f + erff(x * 0.70710678118654752f));
                Hout[(size_t)row * H1 + col] = f2bf(g);
            }
}

// ---------------- GEMM2 (batched): (24576 x 384) @ w2t^T (256 x 384) ---------
__global__ __launch_bounds__(256) void k_gemm2(const unsigned short* __restrict__ A,
                                               const unsigned short* __restrict__ Bt,
                                               const float* __restrict__ b2,
                                               float* __restrict__ outp) {
    __shared__ unsigned char As[16384];   // 128 x 128B
    __shared__ unsigned char Bs[8192];    // 64 x 128B
    int bm = blockIdx.x % (MTOT / 128), bn = blockIdx.x / (MTOT / 128);
    int tid = threadIdx.x, lane = tid & 63;
    int wid = tid >> 6, wm = wid & 1, wn = wid >> 1;
    int l15 = lane & 15, hi = lane >> 4;
    f32x4 acc[4][2] = {};
    const unsigned short* Abase = A + (size_t)(bm * 128) * H1;
    const unsigned short* Bbase = Bt + (size_t)(bn * 64) * H1;
    for (int kt = 0; kt < H1 / 64; ++kt) {
#pragma unroll
        for (int q = 0; q < 4; ++q) {
            int e = (wid * 4 + q) * 64 + lane;
            int row = e >> 3, su = (e & 7) ^ (row & 7);
            GLOAD16(Abase + (size_t)row * H1 + kt * 64 + su * 8, As + (wid * 4 + q) * 1024);
        }
#pragma unroll
        for (int q = 0; q < 2; ++q) {
            int e = (wid * 2 + q) * 64 + lane;
            int row = e >> 3, su = (e & 7) ^ (row & 7);
            GLOAD16(Bbase + (size_t)row * H1 + kt * 64 + su * 8, Bs + (wid * 2 + q) * 1024);
        }
        __syncthreads();
#pragma unroll
        for (int ks = 0; ks < 2; ++ks) {
            int colb = ks * 64 + hi * 16;
            bf16x8 a[4], b[2];
#pragma unroll
            for (int km = 0; km < 4; ++km) {
                int arow = wm * 64 + km * 16 + l15;
                a[km] = *(const bf16x8*)(As + arow * 128 + (colb ^ ((arow & 7) << 4)));
            }
#pragma unroll
            for (int ln = 0; ln < 2; ++ln) {
                int brow = wn * 32 + ln * 16 + l15;
                b[ln] = *(const bf16x8*)(Bs + brow * 128 + (colb ^ ((brow & 7) << 4)));
            }
#pragma unroll
            for (int km = 0; km < 4; ++km)
#pragma unroll
                for (int ln = 0; ln < 2; ++ln)
                    acc[km][ln] = __builtin_amdgcn_mfma_f32_16x16x32_bf16(a[km], b[ln], acc[km][ln], 0, 0, 0);
        }
        __syncthreads();
    }
#pragma unroll
    for (int km = 0; km < 4; ++km)
#pragma unroll
        for (int ln = 0; ln < 2; ++ln)
#pragma unroll
            for (int r = 0; r < 4; ++r) {
                int row = bm * 128 + wm * 64 + km * 16 + hi * 4 + r;
                int col = bn * 64 + wn * 32 + ln * 16 + l15;
                int lvl = row / (T_ * N_);
                int r2 = row - lvl * (T_ * N_);
                outp[(size_t)r2 * (4 * OUTC) + lvl * OUTC + col] = acc[km][ln][r] + b2[col];
            }
}

extern "C" void kernel_launch(void* const* d_in, const int* in_sizes, int n_in,
                              void* d_out, int out_size, void* d_ws, size_t ws_size,
                              hipStream_t stream) {
    const float* fmaps   = (const float*)d_in[0];
    const float* coords  = (const float*)d_in[1];
    const float* qcoords = (const float*)d_in[2];
    const int*   qframes = (const int*)d_in[3];
    const float* w1      = (const float*)d_in[4];
    const float* b1      = (const float*)d_in[5];
    const float* w2      = (const float*)d_in[6];
    const float* b2      = (const float*)d_in[7];
    float* outp = (float*)d_out;

    unsigned char* ws = (unsigned char*)d_ws;
    size_t off = 0;
    auto take = [&](size_t bytes) {
        unsigned char* p = ws + off;
        off += (bytes + 255) & ~(size_t)255;
        return p;
    };
    unsigned short* fm0  = (unsigned short*)take((size_t)T_ * H_ * W_ * D_ * 2);
    unsigned short* fm1  = (unsigned short*)take((size_t)T_ * 48 * 64 * D_ * 2);
    unsigned short* fm2  = (unsigned short*)take((size_t)T_ * 24 * 32 * D_ * 2);
    unsigned short* fm3  = (unsigned short*)take((size_t)T_ * 12 * 16 * D_ * 2);
    unsigned short* tfg  = (unsigned short*)take((size_t)4 * N_ * 64 * D_ * 2);
    unsigned short* vol  = (unsigned short*)take((size_t)MTOT * K2 * 2);
    unsigned short* hbuf = (unsigned short*)take((size_t)MTOT * H1 * 2);
    unsigned short* w1t  = (unsigned short*)take((size_t)H1 * K2 * 2);
    unsigned short* w2t  = (unsigned short*)take((size_t)OUTC * H1 * 2);

    hipLaunchKernelGGL(k_w1t, dim3((H1 * K2 + 255) / 256), dim3(256), 0, stream, w1, w1t);
    hipLaunchKernelGGL(k_w2t, dim3((OUTC * H1 + 255) / 256), dim3(256), 0, stream, w2, w2t);
    hipLaunchKernelGGL(k_normalize, dim3(T_ * H_), dim3(256), 0, stream, fmaps, fm0);
    hipLaunchKernelGGL(k_pool, dim3((T_ * 48 * 64 * 32 + 255) / 256), dim3(256), 0, stream, fm0, fm1, 96, 128);
    hipLaunchKernelGGL(k_pool, dim3((T_ * 24 * 32 * 32 + 255) / 256), dim3(256), 0, stream, fm1, fm2, 48, 64);
    hipLaunchKernelGGL(k_pool, dim3((T_ * 12 * 16 * 32 + 255) / 256), dim3(256), 0, stream, fm2, fm3, 24, 32);

    hipLaunchKernelGGL(k_tf, dim3(N_, 4), dim3(256), 0, stream,
                       fm0, fm1, fm2, fm3, qcoords, qframes, tfg);
    hipLaunchKernelGGL(k_cfvol, dim3(N_, T_, 4), dim3(256), 0, stream,
                       fm0, fm1, fm2, fm3, coords, tfg, vol);
    hipLaunchKernelGGL(k_gemm1, dim3((MTOT / 128) * 3), dim3(256), 0, stream, vol, w1t, b1, hbuf);
    hipLaunchKernelGGL(k_gemm2, dim3((MTOT / 128) * 4), dim3(256), 0, stream, hbuf, w2t, b2, outp);
}